// Round 3
// baseline (2202.806 us; speedup 1.0000x reference)
//
#include <hip/hip_runtime.h>
#include <math.h>

// ---------------- Swin block constants (match reference) ----------------
namespace {
constexpr int Hh = 128, Ww = 128, Cc = 192;
constexpr int NHh = 6;
constexpr int Nn = 64, HDd = 32;
constexpr int SH = 4;
constexpr int Mrows = 8 * 128 * 128;   // 131072 tokens
constexpr int NWINtot = 2048;          // windows total
constexpr float LNEPS = 1e-5f;
constexpr float QSCALE = 0.17677669529663687f;  // 32^-0.5
}

// windowed row m (b, wh, ww, th, tw) -> original token index (undo roll -4,-4)
__device__ __forceinline__ int win_row_to_src(int m) {
  int tok = m & 63;
  int wi  = m >> 6;                 // b*256 + wh*16 + ww
  int ww = wi & 15, wh = (wi >> 4) & 15, b = wi >> 8;
  int r = (wh << 3) + (tok >> 3);   // rolled-frame row
  int c = (ww << 3) + (tok & 7);    // rolled-frame col
  int ro = (r + SH) & (Hh - 1);     // roll(-4): rolled[r] = orig[r+4 mod H]
  int co = (c + SH) & (Ww - 1);
  return (b << 14) + (ro << 7) + co;
}

// ---------------- LayerNorm statistics: one wave per row ----------------
__global__ __launch_bounds__(256) void ln_stats_kernel(
    const float* __restrict__ x, float* __restrict__ mu, float* __restrict__ rs) {
  int w = (blockIdx.x * 256 + threadIdx.x) >> 6;
  int lane = threadIdx.x & 63;
  if (w >= Mrows) return;
  const float* row = x + (size_t)w * Cc;
  float v0 = row[lane], v1 = row[lane + 64], v2 = row[lane + 128];
  float s = v0 + v1 + v2;
  float s2 = v0 * v0 + v1 * v1 + v2 * v2;
#pragma unroll
  for (int off = 32; off; off >>= 1) {
    s += __shfl_xor(s, off);
    s2 += __shfl_xor(s2, off);
  }
  if (lane == 0) {
    float m = s * (1.f / Cc);
    float var = s2 * (1.f / Cc) - m * m;   // biased variance
    mu[w] = m;
    rs[w] = rsqrtf(var + LNEPS);
  }
}

// ---------------- expand rel-pos bias table to (NH, 64, 64) ----------------
__global__ __launch_bounds__(256) void rpb_expand_kernel(
    const float* __restrict__ rpb, float* __restrict__ biasF) {
  int t = blockIdx.x * 256 + threadIdx.x;
  if (t >= NHh * Nn * Nn) return;
  int j = t & 63, i = (t >> 6) & 63, h = t >> 12;
  int dh = (i >> 3) - (j >> 3) + 7;
  int dw = (i & 7) - (j & 7) + 7;
  biasF[t] = rpb[(dh * 15 + dw) * NHh + h];
}

// ---------------- generic tiled fp32 GEMM (chunk-aware via m0) ----------------
// BM=128 rows, BN cols, BK=32; 256 threads; micro-tile TM=8 x TN.
// m0 = global row offset of this chunk's row 0.
// AMODE: 0 = plain LOCAL rows from A, 1 = gather(shift+window, GLOBAL row m0+m)+LN from x,
//        2 = LN'd GLOBAL rows (m0+m) from A
// EMODE: 0 = +bias -> local rows, 1 = +bias,gelu -> local rows,
//        2 = +bias,+resid scatter to GLOBAL win_row_to_src(m0+m),
//        3 = +bias,+resid in place at GLOBAL rows (m0+m)
template <int KDIM, int NDIM, int BN, int TN, int AMODE, int EMODE>
__global__ __launch_bounds__(256) void gemm_kernel(
    const float* __restrict__ A, const float* __restrict__ Bw,
    const float* __restrict__ bias,
    const float* __restrict__ mu, const float* __restrict__ rs,
    const float* __restrict__ lnw, const float* __restrict__ lnb,
    const float* resid, float* out, int m0) {
  constexpr int BM = 128, BK = 32, TM = 8;
  __shared__ __align__(16) float As[BK][BM];  // [k][m] so fragment reads are float4 broadcast
  __shared__ __align__(16) float Bs[BK][BN];
  __shared__ int srcI[BM];
  __shared__ float rMu[BM], rRs[BM];

  const int tid = threadIdx.x;
  const int bn = blockIdx.x * BN;  // N-tile on x: consecutive blocks reuse A rows via L2
  const int bm = blockIdx.y * BM;  // local row tile

  if (AMODE == 1) {
    if (tid < BM) {
      int s = win_row_to_src(m0 + bm + tid);
      srcI[tid] = s; rMu[tid] = mu[s]; rRs[tid] = rs[s];
    }
  } else if (AMODE == 2) {
    if (tid < BM) {
      int s = m0 + bm + tid;
      srcI[tid] = s; rMu[tid] = mu[s]; rRs[tid] = rs[s];
    }
  }
  if (AMODE) __syncthreads();

  const int tx = tid & 15, ty = tid >> 4;
  float acc[TM][TN] = {};

  const int arow = tid & 127;          // A row this thread stages
  const int akc = (tid >> 7) * 16;     // k-chunk (0 or 16)
  const float* arowp;
  if (AMODE == 1)      arowp = A + (size_t)srcI[arow] * Cc;
  else if (AMODE == 2) arowp = A + (size_t)srcI[arow] * KDIM;
  else                 arowp = A + (size_t)(bm + arow) * KDIM;
  float lmu = 0.f, lrs = 0.f;
  if (AMODE) { lmu = rMu[arow]; lrs = rRs[arow]; }

  for (int k0 = 0; k0 < KDIM; k0 += BK) {
    // ---- stage A tile (128 x 32): thread loads 16 consecutive k of its row ----
#pragma unroll
    for (int u4 = 0; u4 < 4; ++u4) {
      float4 v = *(const float4*)&arowp[k0 + akc + u4 * 4];
      float vv[4] = {v.x, v.y, v.z, v.w};
#pragma unroll
      for (int e = 0; e < 4; ++e) {
        int kk = akc + u4 * 4 + e;
        float val = vv[e];
        if (AMODE) val = (val - lmu) * lrs * lnw[k0 + kk] + lnb[k0 + kk];
        As[kk][arow] = val;  // bank = row%32 -> 2-way (free)
      }
    }
    // ---- stage B tile (32 x BN) via float4, coalesced ----
    {
      constexpr int NB4 = BN / 4;
      constexpr int ITERS = (BK * NB4) / 256;
#pragma unroll
      for (int it = 0; it < ITERS; ++it) {
        int f = tid + it * 256;
        int kk = f / NB4;
        int n4 = f % NB4;
        int col = bn + n4 * 4;
        float4 v;
        if (NDIM % BN == 0 || col < NDIM)
          v = *(const float4*)&Bw[(size_t)(k0 + kk) * NDIM + col];
        else
          v = make_float4(0.f, 0.f, 0.f, 0.f);
        *(float4*)&Bs[kk][n4 * 4] = v;
      }
    }
    __syncthreads();

#pragma unroll
    for (int kk = 0; kk < BK; ++kk) {
      float a[TM], b[TN];
#pragma unroll
      for (int p = 0; p < TM / 4; ++p)
        *(float4*)&a[p * 4] = *(const float4*)&As[kk][ty * TM + p * 4];
#pragma unroll
      for (int p = 0; p < TN / 4; ++p)
        *(float4*)&b[p * 4] = *(const float4*)&Bs[kk][tx * TN + p * 4];
#pragma unroll
      for (int i = 0; i < TM; ++i)
#pragma unroll
        for (int j = 0; j < TN; ++j) acc[i][j] += a[i] * b[j];
    }
    __syncthreads();
  }

  // ---- epilogue ----
#pragma unroll
  for (int i = 0; i < TM; ++i) {
    int m = bm + ty * TM + i;  // local row
    int dst;                    // row index in `out`
    if (EMODE == 2)      dst = win_row_to_src(m0 + m);
    else if (EMODE == 3) dst = m0 + m;
    else                 dst = m;
#pragma unroll
    for (int p = 0; p < TN / 4; ++p) {
      int col = bn + tx * TN + p * 4;
      if (NDIM % BN != 0 && col >= NDIM) continue;
      float4 o;
      float* op = &o.x;
#pragma unroll
      for (int e = 0; e < 4; ++e) {
        float v = acc[i][p * 4 + e] + bias[col + e];
        if (EMODE == 1) v = 0.5f * v * (1.f + erff(v * 0.70710678118654752f));
        if (EMODE == 2) v += resid[(size_t)dst * NDIM + col + e];
        if (EMODE == 3) v += resid[(size_t)dst * NDIM + col + e];
        op[e] = v;
      }
      *(float4*)&out[(size_t)dst * NDIM + col] = o;
    }
  }
}

// ---------------- windowed attention: one wave per (window, head) ----------------
// qkv/out are chunk-local (window w0+blockIdx.x is global id for the shift mask).
__global__ __launch_bounds__(64) void attn_kernel(
    const float* __restrict__ qkv, const float* __restrict__ biasF,
    float* __restrict__ out, int w0) {
  const int wl = blockIdx.x;       // local window
  const int h = blockIdx.y;
  const int lane = threadIdx.x;    // query token

  __shared__ __align__(16) float Ks[Nn][HDd];
  __shared__ __align__(16) float Vs[Nn][HDd];

  const float* base = qkv + (size_t)wl * Nn * 576;
  {
    const float* kr = base + (size_t)lane * 576 + Cc + h * HDd;
    const float* vr = base + (size_t)lane * 576 + 2 * Cc + h * HDd;
#pragma unroll
    for (int d = 0; d < HDd; d += 4) {
      *(float4*)&Ks[lane][d] = *(const float4*)&kr[d];
      *(float4*)&Vs[lane][d] = *(const float4*)&vr[d];
    }
  }
  float q[HDd];
  {
    const float* qr = base + (size_t)lane * 576 + h * HDd;
#pragma unroll
    for (int d = 0; d < HDd; d += 4) {
      float4 v = *(const float4*)&qr[d];
      q[d] = v.x * QSCALE; q[d + 1] = v.y * QSCALE;
      q[d + 2] = v.z * QSCALE; q[d + 3] = v.w * QSCALE;
    }
  }
  // scores init = rel-pos bias + shift mask
  float s[Nn];
  {
    const float* bp = biasF + ((size_t)h * Nn + lane) * Nn;
#pragma unroll
    for (int j = 0; j < Nn; j += 4) {
      float4 v = *(const float4*)&bp[j];
      s[j] = v.x; s[j + 1] = v.y; s[j + 2] = v.z; s[j + 3] = v.w;
    }
  }
  {
    int wi = (w0 + wl) & 255;
    int wh = wi >> 4, ww = wi & 15;
    int ri = wh * 8 + (lane >> 3), ci = ww * 8 + (lane & 7);
    int regi = (ri < 120 ? 0 : (ri < 124 ? 1 : 2)) * 3 + (ci < 120 ? 0 : (ci < 124 ? 1 : 2));
#pragma unroll
    for (int j = 0; j < Nn; ++j) {
      int rj = wh * 8 + (j >> 3), cj = ww * 8 + (j & 7);
      int regj = (rj < 120 ? 0 : (rj < 124 ? 1 : 2)) * 3 + (cj < 120 ? 0 : (cj < 124 ? 1 : 2));
      if (regj != regi) s[j] -= 100.f;
    }
  }
  __syncthreads();

  // QK^T: 4 independent accumulator chains for ILP; Ks reads are wave-broadcast (free)
#pragma unroll
  for (int j = 0; j < Nn; j += 4) {
    float a0 = s[j], a1 = s[j + 1], a2 = s[j + 2], a3 = s[j + 3];
#pragma unroll
    for (int d = 0; d < HDd; ++d) {
      float qd = q[d];
      a0 += qd * Ks[j][d];
      a1 += qd * Ks[j + 1][d];
      a2 += qd * Ks[j + 2][d];
      a3 += qd * Ks[j + 3][d];
    }
    s[j] = a0; s[j + 1] = a1; s[j + 2] = a2; s[j + 3] = a3;
  }
  float mx = -1e30f;
#pragma unroll
  for (int j = 0; j < Nn; ++j) mx = fmaxf(mx, s[j]);
  float sum = 0.f;
#pragma unroll
  for (int j = 0; j < Nn; ++j) {
    float e = expf(s[j] - mx);
    s[j] = e;
    sum += e;
  }
  float inv = 1.f / sum;
  float o[HDd] = {};
#pragma unroll
  for (int j = 0; j < Nn; ++j) {
    float p = s[j];
#pragma unroll
    for (int d = 0; d < HDd; ++d) o[d] += p * Vs[j][d];
  }
  {
    float* orow = out + ((size_t)wl * Nn + lane) * Cc + h * HDd;
#pragma unroll
    for (int d = 0; d < HDd; d += 4) {
      float4 v = make_float4(o[d] * inv, o[d + 1] * inv, o[d + 2] * inv, o[d + 3] * inv);
      *(float4*)&orow[d] = v;
    }
  }
}

// ---------------- host launch ----------------
extern "C" void kernel_launch(void* const* d_in, const int* in_sizes, int n_in,
                              void* d_out, int out_size, void* d_ws, size_t ws_size,
                              hipStream_t stream) {
  const float* x     = (const float*)d_in[0];
  const float* ln1w  = (const float*)d_in[1];
  const float* ln1b  = (const float*)d_in[2];
  const float* qkvw  = (const float*)d_in[3];
  const float* qkvb  = (const float*)d_in[4];
  const float* rpb   = (const float*)d_in[5];
  const float* projw = (const float*)d_in[6];
  const float* projb = (const float*)d_in[7];
  const float* ln2w  = (const float*)d_in[8];
  const float* ln2b  = (const float*)d_in[9];
  const float* fc1w  = (const float*)d_in[10];
  const float* fc1b  = (const float*)d_in[11];
  const float* fc2w  = (const float*)d_in[12];
  const float* fc2b  = (const float*)d_in[13];
  float* out = (float*)d_out;

  // Fixed small scratch: mu 512KB | rs 512KB | biasF 96KB  (= 1146880 B)
  char* ws = (char*)d_ws;
  float* mu    = (float*)(ws);
  float* rs    = (float*)(ws + 524288);
  float* biasF = (float*)(ws + 1048576);
  char*  big   = ws + 1146880;
  size_t R = (ws_size > 1146880) ? ws_size - 1146880 : 0;

  // Chunk sizing from available scratch (deterministic in ws_size).
  // Window phase: per window 64*576*4 (qkv) + 64*192*4 (attn_out) = 196608 B.
  long long wch = (long long)(R / 196608);
  if (wch > NWINtot) wch = NWINtot;
  wch &= ~1LL;            // keep rows divisible by BM=128
  if (wch < 2) wch = 2;   // floor; below this nothing fits anyway
  // MLP phase: per row 768*4 = 3072 B.
  long long rch = (long long)(R / 3072);
  if (rch > Mrows) rch = Mrows;
  rch &= ~127LL;
  if (rch < 128) rch = 128;

  // 1) LN1 stats on x
  ln_stats_kernel<<<Mrows / 4, 256, 0, stream>>>(x, mu, rs);
  // 2) dense rel-pos bias
  rpb_expand_kernel<<<96, 256, 0, stream>>>(rpb, biasF);

  // 3-5) window phase, chunked: QKV GEMM -> attention -> proj(+resid scatter)
  float* qkvc = (float*)big;
  float* aoc  = (float*)(big + (size_t)wch * 147456);  // fixed offset (max chunk)
  for (int w = 0; w < NWINtot; w += (int)wch) {
    int cur = (NWINtot - w < (int)wch) ? (NWINtot - w) : (int)wch;
    int rowsc = cur * 64;
    gemm_kernel<192, 576, 128, 8, 1, 0><<<dim3(5, rowsc / 128), 256, 0, stream>>>(
        x, qkvw, qkvb, mu, rs, ln1w, ln1b, nullptr, qkvc, w * 64);
    attn_kernel<<<dim3(cur, NHh), 64, 0, stream>>>(qkvc, biasF, aoc, w);
    gemm_kernel<192, 192, 64, 4, 0, 2><<<dim3(3, rowsc / 128), 256, 0, stream>>>(
        aoc, projw, projb, nullptr, nullptr, nullptr, nullptr, x, out, w * 64);
  }

  // 6) LN2 stats on x2 (all rows final before any fc2 touches them)
  ln_stats_kernel<<<Mrows / 4, 256, 0, stream>>>(out, mu, rs);

  // 7-8) MLP, chunked by rows (chunks touch disjoint rows -> no RAW hazard)
  float* h1c = (float*)big;
  for (int r = 0; r < Mrows; r += (int)rch) {
    int cur = (Mrows - r < (int)rch) ? (Mrows - r) : (int)rch;
    gemm_kernel<192, 768, 128, 8, 2, 1><<<dim3(6, cur / 128), 256, 0, stream>>>(
        out, fc1w, fc1b, mu, rs, ln2w, ln2b, nullptr, h1c, r);
    gemm_kernel<768, 192, 64, 4, 0, 3><<<dim3(3, cur / 128), 256, 0, stream>>>(
        h1c, fc2w, fc2b, nullptr, nullptr, nullptr, nullptr, out, out, r);
  }
}

// Round 4
// 1103.968 us; speedup vs baseline: 1.9954x; 1.9954x over previous
//
#include <hip/hip_runtime.h>
#include <math.h>

typedef _Float16 f16;
typedef _Float16 f16x8 __attribute__((ext_vector_type(8)));
typedef float f32x4 __attribute__((ext_vector_type(4)));

// ---------------- Swin block constants (match reference) ----------------
namespace {
constexpr int Hh = 128, Ww = 128, Cc = 192;
constexpr int NHh = 6;
constexpr int Nn = 64, HDd = 32;
constexpr int SH = 4;
constexpr int Mrows = 131072;
constexpr int NWINtot = 2048;
constexpr float LNEPS = 1e-5f;
constexpr float QSCALE = 0.17677669529663687f;  // 32^-0.5
}

// windowed row m -> original token index (undo roll -4,-4)
__device__ __forceinline__ int win_row_to_src(int m) {
  int tok = m & 63;
  int wi  = m >> 6;
  int ww = wi & 15, wh = (wi >> 4) & 15, b = wi >> 8;
  int r = (wh << 3) + (tok >> 3);
  int c = (ww << 3) + (tok & 7);
  int ro = (r + SH) & (Hh - 1);
  int co = (c + SH) & (Ww - 1);
  return (b << 14) + (ro << 7) + co;
}

// ---------------- LayerNorm statistics: one wave per row ----------------
__global__ __launch_bounds__(256) void ln_stats_kernel(
    const float* __restrict__ x, float* __restrict__ mu, float* __restrict__ rs) {
  int w = (blockIdx.x * 256 + threadIdx.x) >> 6;
  int lane = threadIdx.x & 63;
  if (w >= Mrows) return;
  const float* row = x + (size_t)w * Cc;
  float v0 = row[lane], v1 = row[lane + 64], v2 = row[lane + 128];
  float s = v0 + v1 + v2;
  float s2 = v0 * v0 + v1 * v1 + v2 * v2;
#pragma unroll
  for (int off = 32; off; off >>= 1) {
    s += __shfl_xor(s, off);
    s2 += __shfl_xor(s2, off);
  }
  if (lane == 0) {
    float m = s * (1.f / Cc);
    float var = s2 * (1.f / Cc) - m * m;
    mu[w] = m;
    rs[w] = rsqrtf(var + LNEPS);
  }
}

// ---------------- expand rel-pos bias table to (NH, 64, 64) ----------------
__global__ __launch_bounds__(256) void rpb_expand_kernel(
    const float* __restrict__ rpb, float* __restrict__ biasF) {
  int t = blockIdx.x * 256 + threadIdx.x;
  if (t >= NHh * Nn * Nn) return;
  int j = t & 63, i = (t >> 6) & 63, h = t >> 12;
  int dh = (i >> 3) - (j >> 3) + 7;
  int dw = (i & 7) - (j & 7) + 7;
  biasF[t] = rpb[(dh * 15 + dw) * NHh + h];
}

// ---------------- weight transpose + fp16 hi/lo split: W[K][N] -> Wt[N][K] ----------------
__global__ __launch_bounds__(256) void wconv_kernel(
    const float* __restrict__ W, f16* __restrict__ hi, f16* __restrict__ lo,
    int K, int N) {
  int idx = blockIdx.x * 256 + threadIdx.x;  // = n*K + k (k fastest -> coalesced writes)
  if (idx >= K * N) return;
  int n = idx / K, k = idx - n * K;
  float w = W[(size_t)k * N + n];
  f16 h = (f16)w;
  hi[idx] = h;
  lo[idx] = (f16)(w - (float)h);
}

// ---------------- MFMA GEMM, fp16x3 split precision ----------------
// BM=128, BN=192, BK=64; 512 threads = 8 waves (2 M x 4 N); per-wave 64x48 out.
// A staged in fragment-major LDS (conflict-free b128 reads); B fragments loaded
// direct global->reg from pre-transposed fp16 hi/lo weights [N][K].
// AMODE: 0 = plain fp32 local rows; 1 = gather(shift+window)+LN from x (global m0+m);
//        2 = LN fp32 global rows (m0+m); 3 = plain fp16 local rows (no A-lo, 2-term mfma)
// EMODE: 0 = +bias -> fp32 local rows; 1 = +bias,gelu -> fp16 local rows;
//        2 = +bias+resid scatter to win_row_to_src(m0+m); 3 = +bias+resid at global rows m0+m
template <int KDIM, int NDIM, int AMODE, int EMODE>
__global__ __launch_bounds__(512, 4) void gemm_mfma(
    const void* __restrict__ Ain, const f16* __restrict__ BtHi,
    const f16* __restrict__ BtLo, const float* __restrict__ bias,
    const float* __restrict__ mu, const float* __restrict__ rs,
    const float* __restrict__ lnw, const float* __restrict__ lnb,
    const float* __restrict__ resid, void* __restrict__ outp, int m0) {
  constexpr int BM = 128, BK = 64;
  constexpr bool A16 = (AMODE == 3);
  // 32 subtiles (prec 2 x ks 2 x rowgroup 8), each 16x32 fp16 = 1024 B, stride 1040 (bank rotate)
  __shared__ __align__(16) char lds[32 * 1040];

  const int tid = threadIdx.x;
  const int bn = blockIdx.x * 192;
  const int bm = blockIdx.y * BM;
  const int lane = tid & 63;
  const int wid = tid >> 6;
  const int wr = wid & 1, wc = wid >> 1;

  // staging coords: 4 threads per row, 16 consecutive k each (coalesced 64B/thread)
  const int srow = tid >> 2;
  const int kq = tid & 3;

  const float* arow32 = nullptr;
  const f16* arow16 = nullptr;
  float lmu = 0.f, lrs = 1.f;
  if (AMODE == 0) {
    arow32 = (const float*)Ain + (size_t)(bm + srow) * KDIM;
  } else if (AMODE == 1) {
    int s = win_row_to_src(m0 + bm + srow);
    arow32 = (const float*)Ain + (size_t)s * Cc;
    lmu = mu[s]; lrs = rs[s];
  } else if (AMODE == 2) {
    int s = m0 + bm + srow;
    arow32 = (const float*)Ain + (size_t)s * KDIM;
    lmu = mu[s]; lrs = rs[s];
  } else {
    arow16 = (const f16*)Ain + (size_t)(bm + srow) * KDIM;
  }

  f32x4 acc[4][3];
#pragma unroll
  for (int i = 0; i < 4; ++i)
#pragma unroll
    for (int j = 0; j < 3; ++j) acc[i][j] = (f32x4){0.f, 0.f, 0.f, 0.f};

  for (int k0 = 0; k0 < KDIM; k0 += BK) {
    // ---- stage A tile (128 x 64) into fragment-major LDS ----
    {
      const int g = srow >> 4;
      const int ks = kq >> 1;
      const int h0 = (kq & 1) * 2;
      const int slot = srow & 15;
      if (!A16) {
        f16x8 vh0, vh1, vl0, vl1;
#pragma unroll
        for (int u = 0; u < 4; ++u) {
          float4 v = *(const float4*)&arow32[k0 + kq * 16 + u * 4];
          float vv[4] = {v.x, v.y, v.z, v.w};
#pragma unroll
          for (int e = 0; e < 4; ++e) {
            float val = vv[e];
            if (AMODE) val = (val - lmu) * lrs * lnw[k0 + kq * 16 + u * 4 + e] + lnb[k0 + kq * 16 + u * 4 + e];
            f16 hi = (f16)val;
            f16 lo = (f16)(val - (float)hi);
            if (u < 2) { vh0[u * 4 + e] = hi; vl0[u * 4 + e] = lo; }
            else       { vh1[(u - 2) * 4 + e] = hi; vl1[(u - 2) * 4 + e] = lo; }
          }
        }
        char* sb0 = lds + (0 * 16 + ks * 8 + g) * 1040;
        char* sb1 = lds + (1 * 16 + ks * 8 + g) * 1040;
        *(f16x8*)(sb0 + (slot | ((h0 + 0) << 4)) * 16) = vh0;
        *(f16x8*)(sb0 + (slot | ((h0 + 1) << 4)) * 16) = vh1;
        *(f16x8*)(sb1 + (slot | ((h0 + 0) << 4)) * 16) = vl0;
        *(f16x8*)(sb1 + (slot | ((h0 + 1) << 4)) * 16) = vl1;
      } else {
        f16x8 w0 = *(const f16x8*)&arow16[k0 + kq * 16];
        f16x8 w1 = *(const f16x8*)&arow16[k0 + kq * 16 + 8];
        char* sb0 = lds + (ks * 8 + g) * 1040;
        *(f16x8*)(sb0 + (slot | ((h0 + 0) << 4)) * 16) = w0;
        *(f16x8*)(sb0 + (slot | ((h0 + 1) << 4)) * 16) = w1;
      }
    }
    __syncthreads();

    // ---- compute: per ks, load B frags (global, L2) then MFMA over 4x3 tiles ----
#pragma unroll
    for (int ks = 0; ks < 2; ++ks) {
      const int kk = k0 + ks * 32 + (lane >> 4) * 8;
      f16x8 bh[3], bl[3];
#pragma unroll
      for (int ni = 0; ni < 3; ++ni) {
        int n = bn + wc * 48 + ni * 16 + (lane & 15);
        bh[ni] = *(const f16x8*)&BtHi[(size_t)n * KDIM + kk];
        bl[ni] = *(const f16x8*)&BtLo[(size_t)n * KDIM + kk];
      }
#pragma unroll
      for (int mi = 0; mi < 4; ++mi) {
        const int g = wr * 4 + mi;
        f16x8 ah = *(const f16x8*)(lds + (0 * 16 + ks * 8 + g) * 1040 + lane * 16);
        f16x8 al;
        if (!A16) al = *(const f16x8*)(lds + (1 * 16 + ks * 8 + g) * 1040 + lane * 16);
#pragma unroll
        for (int ni = 0; ni < 3; ++ni) {
          acc[mi][ni] = __builtin_amdgcn_mfma_f32_16x16x32_f16(ah, bh[ni], acc[mi][ni], 0, 0, 0);
          acc[mi][ni] = __builtin_amdgcn_mfma_f32_16x16x32_f16(ah, bl[ni], acc[mi][ni], 0, 0, 0);
          if (!A16)
            acc[mi][ni] = __builtin_amdgcn_mfma_f32_16x16x32_f16(al, bh[ni], acc[mi][ni], 0, 0, 0);
        }
      }
    }
    __syncthreads();
  }

  // ---- epilogue: C/D layout col=lane&15, row=(lane>>4)*4+r ----
#pragma unroll
  for (int mi = 0; mi < 4; ++mi) {
#pragma unroll
    for (int ni = 0; ni < 3; ++ni) {
      int col = bn + wc * 48 + ni * 16 + (lane & 15);
      float bcol = bias[col];
#pragma unroll
      for (int r = 0; r < 4; ++r) {
        int ml = bm + wr * 64 + mi * 16 + (lane >> 4) * 4 + r;  // local row
        float v = acc[mi][ni][r] + bcol;
        if (EMODE == 0) {
          ((float*)outp)[(size_t)ml * NDIM + col] = v;
        } else if (EMODE == 1) {
          v = 0.5f * v * (1.f + erff(v * 0.70710678118654752f));
          ((f16*)outp)[(size_t)ml * NDIM + col] = (f16)v;
        } else if (EMODE == 2) {
          int dst = win_row_to_src(m0 + ml);
          ((float*)outp)[(size_t)dst * NDIM + col] = v + resid[(size_t)dst * NDIM + col];
        } else {
          int dst = m0 + ml;
          ((float*)outp)[(size_t)dst * NDIM + col] = v + resid[(size_t)dst * NDIM + col];
        }
      }
    }
  }
}

// ---------------- windowed attention: one wave per (window, head) ----------------
__global__ __launch_bounds__(64) void attn_kernel(
    const float* __restrict__ qkv, const float* __restrict__ biasF,
    float* __restrict__ out, int w0) {
  const int wl = blockIdx.x;
  const int h = blockIdx.y;
  const int lane = threadIdx.x;

  __shared__ __align__(16) float Ks[Nn][HDd];
  __shared__ __align__(16) float Vs[Nn][HDd];

  const float* base = qkv + (size_t)wl * Nn * 576;
  {
    const float* kr = base + (size_t)lane * 576 + Cc + h * HDd;
    const float* vr = base + (size_t)lane * 576 + 2 * Cc + h * HDd;
#pragma unroll
    for (int d = 0; d < HDd; d += 4) {
      *(float4*)&Ks[lane][d] = *(const float4*)&kr[d];
      *(float4*)&Vs[lane][d] = *(const float4*)&vr[d];
    }
  }
  float q[HDd];
  {
    const float* qr = base + (size_t)lane * 576 + h * HDd;
#pragma unroll
    for (int d = 0; d < HDd; d += 4) {
      float4 v = *(const float4*)&qr[d];
      q[d] = v.x * QSCALE; q[d + 1] = v.y * QSCALE;
      q[d + 2] = v.z * QSCALE; q[d + 3] = v.w * QSCALE;
    }
  }
  float s[Nn];
  {
    const float* bp = biasF + ((size_t)h * Nn + lane) * Nn;
#pragma unroll
    for (int j = 0; j < Nn; j += 4) {
      float4 v = *(const float4*)&bp[j];
      s[j] = v.x; s[j + 1] = v.y; s[j + 2] = v.z; s[j + 3] = v.w;
    }
  }
  {
    int wi = (w0 + wl) & 255;
    int wh = wi >> 4, ww = wi & 15;
    int ri = wh * 8 + (lane >> 3), ci = ww * 8 + (lane & 7);
    int regi = (ri < 120 ? 0 : (ri < 124 ? 1 : 2)) * 3 + (ci < 120 ? 0 : (ci < 124 ? 1 : 2));
#pragma unroll
    for (int j = 0; j < Nn; ++j) {
      int rj = wh * 8 + (j >> 3), cj = ww * 8 + (j & 7);
      int regj = (rj < 120 ? 0 : (rj < 124 ? 1 : 2)) * 3 + (cj < 120 ? 0 : (cj < 124 ? 1 : 2));
      if (regj != regi) s[j] -= 100.f;
    }
  }
  __syncthreads();

#pragma unroll
  for (int j = 0; j < Nn; j += 4) {
    float a0 = s[j], a1 = s[j + 1], a2 = s[j + 2], a3 = s[j + 3];
#pragma unroll
    for (int d = 0; d < HDd; ++d) {
      float qd = q[d];
      a0 += qd * Ks[j][d];
      a1 += qd * Ks[j + 1][d];
      a2 += qd * Ks[j + 2][d];
      a3 += qd * Ks[j + 3][d];
    }
    s[j] = a0; s[j + 1] = a1; s[j + 2] = a2; s[j + 3] = a3;
  }
  float mx = -1e30f;
#pragma unroll
  for (int j = 0; j < Nn; ++j) mx = fmaxf(mx, s[j]);
  float sum = 0.f;
#pragma unroll
  for (int j = 0; j < Nn; ++j) {
    float e = expf(s[j] - mx);
    s[j] = e;
    sum += e;
  }
  float inv = 1.f / sum;
  float o[HDd] = {};
#pragma unroll
  for (int j = 0; j < Nn; ++j) {
    float p = s[j];
#pragma unroll
    for (int d = 0; d < HDd; ++d) o[d] += p * Vs[j][d];
  }
  {
    float* orow = out + ((size_t)wl * Nn + lane) * Cc + h * HDd;
#pragma unroll
    for (int d = 0; d < HDd; d += 4) {
      float4 v = make_float4(o[d] * inv, o[d + 1] * inv, o[d + 2] * inv, o[d + 3] * inv);
      *(float4*)&orow[d] = v;
    }
  }
}

// ---------------- host launch ----------------
extern "C" void kernel_launch(void* const* d_in, const int* in_sizes, int n_in,
                              void* d_out, int out_size, void* d_ws, size_t ws_size,
                              hipStream_t stream) {
  const float* x     = (const float*)d_in[0];
  const float* ln1w  = (const float*)d_in[1];
  const float* ln1b  = (const float*)d_in[2];
  const float* qkvw  = (const float*)d_in[3];
  const float* qkvb  = (const float*)d_in[4];
  const float* rpb   = (const float*)d_in[5];
  const float* projw = (const float*)d_in[6];
  const float* projb = (const float*)d_in[7];
  const float* ln2w  = (const float*)d_in[8];
  const float* ln2b  = (const float*)d_in[9];
  const float* fc1w  = (const float*)d_in[10];
  const float* fc1b  = (const float*)d_in[11];
  const float* fc2w  = (const float*)d_in[12];
  const float* fc2b  = (const float*)d_in[13];
  float* out = (float*)d_out;

  // ws: mu 512K | rs 512K | biasF 96K | weight hi/lo fp16 (~1.77MB) | big
  char* ws = (char*)d_ws;
  float* mu    = (float*)ws;
  float* rs    = (float*)(ws + 524288);
  float* biasF = (float*)(ws + 1048576);
  f16* qkvwH = (f16*)(ws + 1146880);  f16* qkvwL = qkvwH + 110592;
  f16* projwH = (f16*)(ws + 1589248); f16* projwL = projwH + 36864;
  f16* fc1wH = (f16*)(ws + 1736704);  f16* fc1wL = fc1wH + 147456;
  f16* fc2wH = (f16*)(ws + 2326528);  f16* fc2wL = fc2wH + 147456;
  char* big  = ws + 2916352;
  size_t R = ws_size > 2916352 ? ws_size - 2916352 : 0;

  // chunk sizing (deterministic in ws_size)
  long long wch = (long long)(R / 196608);   // per window: qkv 147456 + attn_out 49152
  if (wch > NWINtot) wch = NWINtot;
  wch &= ~1LL;
  if (wch < 2) wch = 2;
  long long rch = (long long)(R / 1536);     // per row: h1 fp16 768*2
  if (rch > Mrows) rch = Mrows;
  rch &= ~127LL;
  if (rch < 128) rch = 128;

  // weight pre-transpose+split (tiny)
  wconv_kernel<<<(110592 + 255) / 256, 256, 0, stream>>>(qkvw, qkvwH, qkvwL, 192, 576);
  wconv_kernel<<<144, 256, 0, stream>>>(projw, projwH, projwL, 192, 192);
  wconv_kernel<<<576, 256, 0, stream>>>(fc1w, fc1wH, fc1wL, 192, 768);
  wconv_kernel<<<576, 256, 0, stream>>>(fc2w, fc2wH, fc2wL, 768, 192);

  ln_stats_kernel<<<Mrows / 4, 256, 0, stream>>>(x, mu, rs);
  rpb_expand_kernel<<<96, 256, 0, stream>>>(rpb, biasF);

  // window phase: QKV -> attn -> proj(+resid scatter)
  float* qkvc = (float*)big;
  float* aoc  = (float*)(big + (size_t)wch * 147456);
  for (int w = 0; w < NWINtot; w += (int)wch) {
    int cur = (NWINtot - w < (int)wch) ? (NWINtot - w) : (int)wch;
    int rowsc = cur * 64;
    gemm_mfma<192, 576, 1, 0><<<dim3(3, rowsc / 128), 512, 0, stream>>>(
        x, qkvwH, qkvwL, qkvb, mu, rs, ln1w, ln1b, nullptr, qkvc, w * 64);
    attn_kernel<<<dim3(cur, NHh), 64, 0, stream>>>(qkvc, biasF, aoc, w);
    gemm_mfma<192, 192, 0, 2><<<dim3(1, rowsc / 128), 512, 0, stream>>>(
        aoc, projwH, projwL, projb, nullptr, nullptr, nullptr, nullptr, x, out, w * 64);
  }

  ln_stats_kernel<<<Mrows / 4, 256, 0, stream>>>(out, mu, rs);

  // MLP phase: fc1(+LN2,gelu)->h1 fp16 ; fc2(+resid in place)
  f16* h1c = (f16*)big;
  for (int r = 0; r < Mrows; r += (int)rch) {
    int cur = (Mrows - r < (int)rch) ? (Mrows - r) : (int)rch;
    gemm_mfma<192, 768, 2, 1><<<dim3(4, cur / 128), 512, 0, stream>>>(
        out, fc1wH, fc1wL, fc1b, mu, rs, ln2w, ln2b, nullptr, h1c, r);
    gemm_mfma<768, 192, 3, 3><<<dim3(1, cur / 128), 512, 0, stream>>>(
        h1c, fc2wH, fc2wL, fc2b, nullptr, nullptr, nullptr, nullptr, out, out, r);
  }
}

// Round 5
// 1027.195 us; speedup vs baseline: 2.1445x; 1.0747x over previous
//
#include <hip/hip_runtime.h>
#include <math.h>

typedef _Float16 f16;
typedef _Float16 f16x8 __attribute__((ext_vector_type(8)));
typedef float f32x4 __attribute__((ext_vector_type(4)));

// ---------------- Swin block constants (match reference) ----------------
namespace {
constexpr int Hh = 128, Ww = 128, Cc = 192;
constexpr int NHh = 6;
constexpr int Nn = 64, HDd = 32;
constexpr int SH = 4;
constexpr int Mrows = 131072;
constexpr int NWINtot = 2048;
constexpr float LNEPS = 1e-5f;
constexpr float QSCALE = 0.17677669529663687f;  // 32^-0.5
}

// windowed row m -> original token index (undo roll -4,-4)
__device__ __forceinline__ int win_row_to_src(int m) {
  int tok = m & 63;
  int wi  = m >> 6;
  int ww = wi & 15, wh = (wi >> 4) & 15, b = wi >> 8;
  int r = (wh << 3) + (tok >> 3);
  int c = (ww << 3) + (tok & 7);
  int ro = (r + SH) & (Hh - 1);
  int co = (c + SH) & (Ww - 1);
  return (b << 14) + (ro << 7) + co;
}

// ---------------- fused LN + fp16 convert (+optional window gather) ----------------
// One block = 16 rows. Reads f32 rows (gathered if GATHER), LN-normalizes, writes
// contiguous fp16 rows. Stats computed in-block (read input exactly once).
template <int GATHER>
__global__ __launch_bounds__(256) void ln_prep_kernel(
    const float* __restrict__ X, const float* __restrict__ lnw,
    const float* __restrict__ lnb, f16* __restrict__ outh, int m0) {
  __shared__ float xr[16][192];
  __shared__ float smu[16], srs[16];
  __shared__ int src[16];
  const int t = threadIdx.x;
  const int r0 = blockIdx.x * 16;
  if (t < 16) {
    int m = m0 + r0 + t;
    src[t] = GATHER ? win_row_to_src(m) : m;
  }
  __syncthreads();
  // load 16 rows (768 float4s, 3 per thread), coalesced within each row
#pragma unroll
  for (int it = 0; it < 3; ++it) {
    int f = t + it * 256;
    int row = f / 48, c4 = f - row * 48;
    float4 v = *(const float4*)&X[(size_t)src[row] * 192 + c4 * 4];
    *(float4*)&xr[row][c4 * 4] = v;
  }
  __syncthreads();
  // stats: 4 waves x 4 rows, 16-lane groups
  {
    const int lane = t & 63, w = t >> 6;
    const int g = lane >> 4, li = lane & 15;
    const int row = w * 4 + g;
    float s = 0.f, s2 = 0.f;
#pragma unroll
    for (int j = 0; j < 12; ++j) {
      float v = xr[row][li + j * 16];
      s += v; s2 += v * v;
    }
#pragma unroll
    for (int off = 1; off < 16; off <<= 1) {
      s += __shfl_xor(s, off);
      s2 += __shfl_xor(s2, off);
    }
    if (li == 0) {
      float m = s * (1.f / 192.f);
      smu[row] = m;
      srs[row] = rsqrtf(s2 * (1.f / 192.f) - m * m + LNEPS);
    }
  }
  __syncthreads();
  // write 16*192 fp16 = 384 x 16B chunks, coalesced
#pragma unroll
  for (int it = 0; it < 2; ++it) {
    int c = t + it * 256;
    if (c < 384) {
      int e0 = c * 8;
      int row = e0 / 192, col = e0 - row * 192;
      float mu_ = smu[row], rs_ = srs[row];
      f16x8 o;
#pragma unroll
      for (int j = 0; j < 8; ++j) {
        float v = (xr[row][col + j] - mu_) * rs_ * lnw[col + j] + lnb[col + j];
        o[j] = (f16)v;
      }
      *(f16x8*)&outh[(size_t)(m0 + r0) * 192 + e0] = o;
    }
  }
}

// ---------------- expand rel-pos bias table to (NH, 64, 64) ----------------
__global__ __launch_bounds__(256) void rpb_expand_kernel(
    const float* __restrict__ rpb, float* __restrict__ biasF) {
  int t = blockIdx.x * 256 + threadIdx.x;
  if (t >= NHh * Nn * Nn) return;
  int j = t & 63, i = (t >> 6) & 63, h = t >> 12;
  int dh = (i >> 3) - (j >> 3) + 7;
  int dw = (i & 7) - (j & 7) + 7;
  biasF[t] = rpb[(dh * 15 + dw) * NHh + h];
}

// ---------------- weight transpose + fp16 hi/lo split: W[K][N] -> Wt[N][K] ----------------
__global__ __launch_bounds__(256) void wconv_kernel(
    const float* __restrict__ W, f16* __restrict__ hi, f16* __restrict__ lo,
    int K, int N) {
  int idx = blockIdx.x * 256 + threadIdx.x;
  if (idx >= K * N) return;
  int n = idx / K, k = idx - n * K;
  float w = W[(size_t)k * N + n];
  f16 h = (f16)w;
  hi[idx] = h;
  lo[idx] = (f16)(w - (float)h);
}

// ---------------- MFMA GEMM: A fp16 (pre-converted), B fp16 hi/lo, 2-term ----------------
// BM=128, BN=192, BK=64; 512 threads = 8 waves (2M x 4N); per-wave 64x48 out.
// A staged via pure b128 copies into fragment-major LDS; B frags direct global->reg (L2).
// EMODE: 0 = +bias -> f16 local rows; 1 = +bias,gelu -> f16 local rows;
//        2 = +bias+resid f32 scatter to win_row_to_src(m0e+m); 3 = +bias+resid f32 at m0e+m
template <int KDIM, int NDIM, int EMODE>
__global__ __launch_bounds__(512) void gemm_mfma16(
    const f16* __restrict__ Abase, const f16* __restrict__ BtHi,
    const f16* __restrict__ BtLo, const float* __restrict__ bias,
    const float* __restrict__ resid, void* __restrict__ outp, int m0a, int m0e) {
  // 16 subtiles (ks 2 x rowgroup 8), each 16 rows x 32 k fp16 = 1024 B, stride 1040
  __shared__ __align__(16) char lds[16 * 1040];

  const int tid = threadIdx.x;
  const int bn = blockIdx.x * 192;
  const int bm = blockIdx.y * 128;
  const int lane = tid & 63;
  const int wid = tid >> 6;
  const int wr = wid & 1, wc = wid >> 1;

  // staging: 4 threads/row, 16 consecutive k (32 B) each
  const int srow = tid >> 2;
  const int kq = tid & 3;
  const f16* arow = Abase + (size_t)(m0a + bm + srow) * KDIM;
  const int g = srow >> 4;
  const int ks_st = kq >> 1;
  const int h0 = (kq & 1) * 2;
  const int slot = srow & 15;
  char* sb = lds + (ks_st * 8 + g) * 1040;

  f32x4 acc[4][3];
#pragma unroll
  for (int i = 0; i < 4; ++i)
#pragma unroll
    for (int j = 0; j < 3; ++j) acc[i][j] = (f32x4){0.f, 0.f, 0.f, 0.f};

  for (int k0 = 0; k0 < KDIM; k0 += 64) {
    // ---- stage A tile (128 x 64 fp16): pure copy ----
    {
      f16x8 w0 = *(const f16x8*)&arow[k0 + kq * 16];
      f16x8 w1 = *(const f16x8*)&arow[k0 + kq * 16 + 8];
      *(f16x8*)(sb + (slot | ((h0 + 0) << 4)) * 16) = w0;
      *(f16x8*)(sb + (slot | ((h0 + 1) << 4)) * 16) = w1;
    }
    __syncthreads();

    // ---- compute: per ks load B frags (global, L2-hot), then 4x3 MFMA x 2 terms ----
#pragma unroll
    for (int ks = 0; ks < 2; ++ks) {
      const int kk = k0 + ks * 32 + (lane >> 4) * 8;
      f16x8 bh[3], bl[3];
#pragma unroll
      for (int ni = 0; ni < 3; ++ni) {
        int n = bn + wc * 48 + ni * 16 + (lane & 15);
        bh[ni] = *(const f16x8*)&BtHi[(size_t)n * KDIM + kk];
        bl[ni] = *(const f16x8*)&BtLo[(size_t)n * KDIM + kk];
      }
#pragma unroll
      for (int mi = 0; mi < 4; ++mi) {
        f16x8 ah = *(const f16x8*)(lds + (ks * 8 + wr * 4 + mi) * 1040 + lane * 16);
#pragma unroll
        for (int ni = 0; ni < 3; ++ni) {
          acc[mi][ni] = __builtin_amdgcn_mfma_f32_16x16x32_f16(ah, bh[ni], acc[mi][ni], 0, 0, 0);
          acc[mi][ni] = __builtin_amdgcn_mfma_f32_16x16x32_f16(ah, bl[ni], acc[mi][ni], 0, 0, 0);
        }
      }
    }
    __syncthreads();
  }

  // ---- epilogue: C/D layout col=lane&15, row=(lane>>4)*4+r ----
#pragma unroll
  for (int mi = 0; mi < 4; ++mi) {
#pragma unroll
    for (int ni = 0; ni < 3; ++ni) {
      int col = bn + wc * 48 + ni * 16 + (lane & 15);
      float bcol = bias[col];
#pragma unroll
      for (int r = 0; r < 4; ++r) {
        int ml = bm + wr * 64 + mi * 16 + (lane >> 4) * 4 + r;
        float v = acc[mi][ni][r] + bcol;
        if (EMODE == 0) {
          ((f16*)outp)[(size_t)ml * NDIM + col] = (f16)v;
        } else if (EMODE == 1) {
          v = 0.5f * v * (1.f + erff(v * 0.70710678118654752f));
          ((f16*)outp)[(size_t)ml * NDIM + col] = (f16)v;
        } else if (EMODE == 2) {
          int dst = win_row_to_src(m0e + ml);
          ((float*)outp)[(size_t)dst * NDIM + col] = v + resid[(size_t)dst * NDIM + col];
        } else {
          int dst = m0e + ml;
          ((float*)outp)[(size_t)dst * NDIM + col] = v + resid[(size_t)dst * NDIM + col];
        }
      }
    }
  }
}

// ---------------- windowed attention: one wave per (window, head), fp16 qkv ----------------
__global__ __launch_bounds__(64) void attn_kernel(
    const f16* __restrict__ qkv, const float* __restrict__ biasF,
    f16* __restrict__ out, int w0) {
  const int wl = blockIdx.x;
  const int h = blockIdx.y;
  const int lane = threadIdx.x;

  __shared__ __align__(16) float Ks[Nn][HDd];
  __shared__ __align__(16) float Vs[Nn][HDd];

  const f16* base = qkv + (size_t)wl * Nn * 576;
  {
    const f16* kr = base + (size_t)lane * 576 + Cc + h * HDd;
    const f16* vr = base + (size_t)lane * 576 + 2 * Cc + h * HDd;
#pragma unroll
    for (int d = 0; d < HDd; d += 8) {
      f16x8 kv = *(const f16x8*)&kr[d];
      f16x8 vv = *(const f16x8*)&vr[d];
#pragma unroll
      for (int j = 0; j < 8; ++j) {
        Ks[lane][d + j] = (float)kv[j];
        Vs[lane][d + j] = (float)vv[j];
      }
    }
  }
  float q[HDd];
  {
    const f16* qr = base + (size_t)lane * 576 + h * HDd;
#pragma unroll
    for (int d = 0; d < HDd; d += 8) {
      f16x8 qv = *(const f16x8*)&qr[d];
#pragma unroll
      for (int j = 0; j < 8; ++j) q[d + j] = (float)qv[j] * QSCALE;
    }
  }
  float s[Nn];
  {
    const float* bp = biasF + ((size_t)h * Nn + lane) * Nn;
#pragma unroll
    for (int j = 0; j < Nn; j += 4) {
      float4 v = *(const float4*)&bp[j];
      s[j] = v.x; s[j + 1] = v.y; s[j + 2] = v.z; s[j + 3] = v.w;
    }
  }
  {
    int wi = (w0 + wl) & 255;
    int wh = wi >> 4, ww = wi & 15;
    int ri = wh * 8 + (lane >> 3), ci = ww * 8 + (lane & 7);
    int regi = (ri < 120 ? 0 : (ri < 124 ? 1 : 2)) * 3 + (ci < 120 ? 0 : (ci < 124 ? 1 : 2));
#pragma unroll
    for (int j = 0; j < Nn; ++j) {
      int rj = wh * 8 + (j >> 3), cj = ww * 8 + (j & 7);
      int regj = (rj < 120 ? 0 : (rj < 124 ? 1 : 2)) * 3 + (cj < 120 ? 0 : (cj < 124 ? 1 : 2));
      if (regj != regi) s[j] -= 100.f;
    }
  }
  __syncthreads();

#pragma unroll
  for (int j = 0; j < Nn; j += 4) {
    float a0 = s[j], a1 = s[j + 1], a2 = s[j + 2], a3 = s[j + 3];
#pragma unroll
    for (int d = 0; d < HDd; ++d) {
      float qd = q[d];
      a0 += qd * Ks[j][d];
      a1 += qd * Ks[j + 1][d];
      a2 += qd * Ks[j + 2][d];
      a3 += qd * Ks[j + 3][d];
    }
    s[j] = a0; s[j + 1] = a1; s[j + 2] = a2; s[j + 3] = a3;
  }
  float mx = -1e30f;
#pragma unroll
  for (int j = 0; j < Nn; ++j) mx = fmaxf(mx, s[j]);
  float sum = 0.f;
#pragma unroll
  for (int j = 0; j < Nn; ++j) {
    float e = expf(s[j] - mx);
    s[j] = e;
    sum += e;
  }
  float inv = 1.f / sum;
  float o[HDd] = {};
#pragma unroll
  for (int j = 0; j < Nn; ++j) {
    float p = s[j];
#pragma unroll
    for (int d = 0; d < HDd; ++d) o[d] += p * Vs[j][d];
  }
  {
    f16* orow = out + ((size_t)wl * Nn + lane) * Cc + h * HDd;
#pragma unroll
    for (int d = 0; d < HDd; d += 8) {
      f16x8 v;
#pragma unroll
      for (int j = 0; j < 8; ++j) v[j] = (f16)(o[d + j] * inv);
      *(f16x8*)&orow[d] = v;
    }
  }
}

// ---------------- host launch ----------------
extern "C" void kernel_launch(void* const* d_in, const int* in_sizes, int n_in,
                              void* d_out, int out_size, void* d_ws, size_t ws_size,
                              hipStream_t stream) {
  const float* x     = (const float*)d_in[0];
  const float* ln1w  = (const float*)d_in[1];
  const float* ln1b  = (const float*)d_in[2];
  const float* qkvw  = (const float*)d_in[3];
  const float* qkvb  = (const float*)d_in[4];
  const float* rpb   = (const float*)d_in[5];
  const float* projw = (const float*)d_in[6];
  const float* projb = (const float*)d_in[7];
  const float* ln2w  = (const float*)d_in[8];
  const float* ln2b  = (const float*)d_in[9];
  const float* fc1w  = (const float*)d_in[10];
  const float* fc1b  = (const float*)d_in[11];
  const float* fc2w  = (const float*)d_in[12];
  const float* fc2b  = (const float*)d_in[13];
  float* out = (float*)d_out;

  // ws layout (B): biasF 96K | weights hi/lo fp16 ~1.77M | xh 48M | oh 48M | big
  char* ws = (char*)d_ws;
  float* biasF = (float*)ws;
  f16* qkvwH = (f16*)(ws + 98304);    f16* qkvwL = qkvwH + 110592;
  f16* projwH = (f16*)(ws + 540672);  f16* projwL = projwH + 36864;
  f16* fc1wH = (f16*)(ws + 688128);   f16* fc1wL = fc1wH + 147456;
  f16* fc2wH = (f16*)(ws + 1277952);  f16* fc2wL = fc2wH + 147456;
  f16* xh    = (f16*)(ws + 1867776);                 // 131072x192 f16, window order
  f16* oh    = (f16*)(ws + 1867776 + 50331648);      // 131072x192 f16
  char* big  = ws + 1867776 + 2 * 50331648;
  size_t R = ws_size > (size_t)(1867776 + 2 * 50331648)
                 ? ws_size - (1867776 + 2 * 50331648) : 0;

  // chunk sizing (deterministic in ws_size); known ws fits single-chunk
  long long wch = (long long)(R / 98304);  // per window: qkv16 73728 + ao16 24576
  if (wch > NWINtot) wch = NWINtot;
  wch &= ~1LL;
  if (wch < 2) wch = 2;
  long long rch = (long long)(R / 1536);   // per row: h1 fp16
  if (rch > Mrows) rch = Mrows;
  rch &= ~127LL;
  if (rch < 128) rch = 128;

  // weight transpose + split (tiny)
  wconv_kernel<<<432, 256, 0, stream>>>(qkvw, qkvwH, qkvwL, 192, 576);
  wconv_kernel<<<144, 256, 0, stream>>>(projw, projwH, projwL, 192, 192);
  wconv_kernel<<<576, 256, 0, stream>>>(fc1w, fc1wH, fc1wL, 192, 768);
  wconv_kernel<<<576, 256, 0, stream>>>(fc2w, fc2wH, fc2wL, 768, 192);
  rpb_expand_kernel<<<96, 256, 0, stream>>>(rpb, biasF);

  // LN1 + gather + fp16: x -> xh (window order)
  ln_prep_kernel<1><<<Mrows / 16, 256, 0, stream>>>(x, ln1w, ln1b, xh, 0);

  // window phase: QKV -> attn -> proj(+resid scatter)
  f16* qkvc = (f16*)big;
  f16* aoc  = (f16*)(big + (size_t)wch * 73728);
  for (int w = 0; w < NWINtot; w += (int)wch) {
    int cur = (NWINtot - w < (int)wch) ? (NWINtot - w) : (int)wch;
    int rowsc = cur * 64;
    gemm_mfma16<192, 576, 0><<<dim3(3, rowsc / 128), 512, 0, stream>>>(
        xh, qkvwH, qkvwL, qkvb, nullptr, qkvc, w * 64, 0);
    attn_kernel<<<dim3(cur, NHh), 64, 0, stream>>>(qkvc, biasF, aoc, w);
    gemm_mfma16<192, 192, 2><<<dim3(1, rowsc / 128), 512, 0, stream>>>(
        aoc, projwH, projwL, projb, x, out, 0, w * 64);
  }

  // LN2 + fp16: out -> oh
  ln_prep_kernel<0><<<Mrows / 16, 256, 0, stream>>>(out, ln2w, ln2b, oh, 0);

  // MLP: fc1(+gelu)->h1 f16 ; fc2(+resid in place)
  f16* h1c = (f16*)big;
  for (int r = 0; r < Mrows; r += (int)rch) {
    int cur = (Mrows - r < (int)rch) ? (Mrows - r) : (int)rch;
    gemm_mfma16<192, 768, 1><<<dim3(4, cur / 128), 512, 0, stream>>>(
        oh, fc1wH, fc1wL, fc1b, nullptr, h1c, r, 0);
    gemm_mfma16<768, 192, 3><<<dim3(1, cur / 128), 512, 0, stream>>>(
        h1c, fc2wH, fc2wL, fc2b, out, out, 0, r);
  }
}

// Round 6
// 717.930 us; speedup vs baseline: 3.0683x; 1.4308x over previous
//
#include <hip/hip_runtime.h>
#include <math.h>

typedef _Float16 f16;
typedef _Float16 f16x8 __attribute__((ext_vector_type(8)));
typedef float f32x4 __attribute__((ext_vector_type(4)));

// ---------------- Swin block constants (match reference) ----------------
namespace {
constexpr int Hh = 128, Ww = 128, Cc = 192;
constexpr int NHh = 6;
constexpr int Nn = 64, HDd = 32;
constexpr int SH = 4;
constexpr int Mrows = 131072;
constexpr int NWINtot = 2048;
constexpr float LNEPS = 1e-5f;
constexpr float QSCALE = 0.17677669529663687f;  // 32^-0.5
}

// windowed row m -> original token index (undo roll -4,-4)
__device__ __forceinline__ int win_row_to_src(int m) {
  int tok = m & 63;
  int wi  = m >> 6;
  int ww = wi & 15, wh = (wi >> 4) & 15, b = wi >> 8;
  int r = (wh << 3) + (tok >> 3);
  int c = (ww << 3) + (tok & 7);
  int ro = (r + SH) & (Hh - 1);
  int co = (c + SH) & (Ww - 1);
  return (b << 14) + (ro << 7) + co;
}

// ---------------- fused LN + fp16 convert (+optional window gather) ----------------
template <int GATHER>
__global__ __launch_bounds__(256) void ln_prep_kernel(
    const float* __restrict__ X, const float* __restrict__ lnw,
    const float* __restrict__ lnb, f16* __restrict__ outh, int m0) {
  __shared__ float xr[16][192];
  __shared__ float smu[16], srs[16];
  __shared__ int src[16];
  const int t = threadIdx.x;
  const int r0 = blockIdx.x * 16;
  if (t < 16) {
    int m = m0 + r0 + t;
    src[t] = GATHER ? win_row_to_src(m) : m;
  }
  __syncthreads();
#pragma unroll
  for (int it = 0; it < 3; ++it) {
    int f = t + it * 256;
    int row = f / 48, c4 = f - row * 48;
    float4 v = *(const float4*)&X[(size_t)src[row] * 192 + c4 * 4];
    *(float4*)&xr[row][c4 * 4] = v;
  }
  __syncthreads();
  {
    const int lane = t & 63, w = t >> 6;
    const int g = lane >> 4, li = lane & 15;
    const int row = w * 4 + g;
    float s = 0.f, s2 = 0.f;
#pragma unroll
    for (int j = 0; j < 12; ++j) {
      float v = xr[row][li + j * 16];
      s += v; s2 += v * v;
    }
#pragma unroll
    for (int off = 1; off < 16; off <<= 1) {
      s += __shfl_xor(s, off);
      s2 += __shfl_xor(s2, off);
    }
    if (li == 0) {
      float m = s * (1.f / 192.f);
      smu[row] = m;
      srs[row] = rsqrtf(s2 * (1.f / 192.f) - m * m + LNEPS);
    }
  }
  __syncthreads();
#pragma unroll
  for (int it = 0; it < 2; ++it) {
    int c = t + it * 256;
    if (c < 384) {
      int e0 = c * 8;
      int row = e0 / 192, col = e0 - row * 192;
      float mu_ = smu[row], rs_ = srs[row];
      f16x8 o;
#pragma unroll
      for (int j = 0; j < 8; ++j) {
        float v = (xr[row][col + j] - mu_) * rs_ * lnw[col + j] + lnb[col + j];
        o[j] = (f16)v;
      }
      *(f16x8*)&outh[(size_t)(m0 + r0) * 192 + e0] = o;
    }
  }
}

// ---------------- rel-pos bias in MFMA fragment layout: [h][it][jt][lane][r] ----------------
__global__ __launch_bounds__(256) void rpb_expand_kernel(
    const float* __restrict__ rpb, float* __restrict__ biasF2) {
  int t = blockIdx.x * 256 + threadIdx.x;
  if (t >= NHh * 4 * 4 * 64 * 4) return;
  int r = t & 3, lane = (t >> 2) & 63, jt = (t >> 8) & 3, it = (t >> 10) & 3, h = t >> 12;
  int row = it * 16 + (lane >> 4) * 4 + r;
  int col = jt * 16 + (lane & 15);
  int dh = (row >> 3) - (col >> 3) + 7;
  int dw = (row & 7) - (col & 7) + 7;
  biasF2[t] = rpb[(dh * 15 + dw) * NHh + h];
}

// ---------------- weight transpose + fp16 hi/lo split: W[K][N] -> Wt[N][K] ----------------
__global__ __launch_bounds__(256) void wconv_kernel(
    const float* __restrict__ W, f16* __restrict__ hi, f16* __restrict__ lo,
    int K, int N) {
  int idx = blockIdx.x * 256 + threadIdx.x;
  if (idx >= K * N) return;
  int n = idx / K, k = idx - n * K;
  float w = W[(size_t)k * N + n];
  f16 h = (f16)w;
  hi[idx] = h;
  lo[idx] = (f16)(w - (float)h);
}

// ---------------- MFMA GEMM: A fp16 (pre-converted), B fp16 hi/lo, 2-term ----------------
template <int KDIM, int NDIM, int EMODE>
__global__ __launch_bounds__(512) void gemm_mfma16(
    const f16* __restrict__ Abase, const f16* __restrict__ BtHi,
    const f16* __restrict__ BtLo, const float* __restrict__ bias,
    const float* __restrict__ resid, void* __restrict__ outp, int m0a, int m0e) {
  __shared__ __align__(16) char lds[16 * 1040];

  const int tid = threadIdx.x;
  const int bn = blockIdx.x * 192;
  const int bm = blockIdx.y * 128;
  const int lane = tid & 63;
  const int wid = tid >> 6;
  const int wr = wid & 1, wc = wid >> 1;

  const int srow = tid >> 2;
  const int kq = tid & 3;
  const f16* arow = Abase + (size_t)(m0a + bm + srow) * KDIM;
  const int g = srow >> 4;
  const int ks_st = kq >> 1;
  const int h0 = (kq & 1) * 2;
  const int slot = srow & 15;
  char* sb = lds + (ks_st * 8 + g) * 1040;

  f32x4 acc[4][3];
#pragma unroll
  for (int i = 0; i < 4; ++i)
#pragma unroll
    for (int j = 0; j < 3; ++j) acc[i][j] = (f32x4){0.f, 0.f, 0.f, 0.f};

  for (int k0 = 0; k0 < KDIM; k0 += 64) {
    {
      f16x8 w0 = *(const f16x8*)&arow[k0 + kq * 16];
      f16x8 w1 = *(const f16x8*)&arow[k0 + kq * 16 + 8];
      *(f16x8*)(sb + (slot | ((h0 + 0) << 4)) * 16) = w0;
      *(f16x8*)(sb + (slot | ((h0 + 1) << 4)) * 16) = w1;
    }
    __syncthreads();

#pragma unroll
    for (int ks = 0; ks < 2; ++ks) {
      const int kk = k0 + ks * 32 + (lane >> 4) * 8;
      f16x8 bh[3], bl[3];
#pragma unroll
      for (int ni = 0; ni < 3; ++ni) {
        int n = bn + wc * 48 + ni * 16 + (lane & 15);
        bh[ni] = *(const f16x8*)&BtHi[(size_t)n * KDIM + kk];
        bl[ni] = *(const f16x8*)&BtLo[(size_t)n * KDIM + kk];
      }
#pragma unroll
      for (int mi = 0; mi < 4; ++mi) {
        f16x8 ah = *(const f16x8*)(lds + (ks * 8 + wr * 4 + mi) * 1040 + lane * 16);
#pragma unroll
        for (int ni = 0; ni < 3; ++ni) {
          acc[mi][ni] = __builtin_amdgcn_mfma_f32_16x16x32_f16(ah, bh[ni], acc[mi][ni], 0, 0, 0);
          acc[mi][ni] = __builtin_amdgcn_mfma_f32_16x16x32_f16(ah, bl[ni], acc[mi][ni], 0, 0, 0);
        }
      }
    }
    __syncthreads();
  }

#pragma unroll
  for (int mi = 0; mi < 4; ++mi) {
#pragma unroll
    for (int ni = 0; ni < 3; ++ni) {
      int col = bn + wc * 48 + ni * 16 + (lane & 15);
      float bcol = bias[col];
#pragma unroll
      for (int r = 0; r < 4; ++r) {
        int ml = bm + wr * 64 + mi * 16 + (lane >> 4) * 4 + r;
        float v = acc[mi][ni][r] + bcol;
        if (EMODE == 0) {
          ((f16*)outp)[(size_t)ml * NDIM + col] = (f16)v;
        } else if (EMODE == 1) {
          v = 0.5f * v * (1.f + erff(v * 0.70710678118654752f));
          ((f16*)outp)[(size_t)ml * NDIM + col] = (f16)v;
        } else if (EMODE == 2) {
          int dst = win_row_to_src(m0e + ml);
          ((float*)outp)[(size_t)dst * NDIM + col] = v + resid[(size_t)dst * NDIM + col];
        } else {
          int dst = m0e + ml;
          ((float*)outp)[(size_t)dst * NDIM + col] = v + resid[(size_t)dst * NDIM + col];
        }
      }
    }
  }
}

// ---------------- MFMA windowed attention: block = 1 window x 6 heads (384 thr) ----------------
// Per wave (one head): S = QK^T via 16 mfma; bias(frag-layout)+mask+scale in-reg;
// row-max via 16-lane shfl; exp; P -> swizzled LDS f16; PV + row-sum-via-ones mfma.
// No __syncthreads: every wave reads only LDS it wrote.
__global__ __launch_bounds__(384) void attn_mfma(
    const f16* __restrict__ qkv, const float* __restrict__ biasF2,
    f16* __restrict__ out, int w0) {
  __shared__ f16 Vt[192 * 64];       // [d][tok], 16B-chunk XOR swizzle
  __shared__ f16 Pb[NHh][64 * 64];   // per-wave P, same swizzle
  const int t = threadIdx.x;
  const int h = t >> 6;
  const int lane = t & 63;
  const int g = lane >> 4, l15 = lane & 15;
  const int wl = blockIdx.x;
  const f16* base = qkv + (size_t)wl * 64 * 576;

  // ---- stage V^T for this head: tok = lane, d = h*32 .. +31 ----
  {
    const f16* vr = base + (size_t)lane * 576 + 384 + h * 32;
    f16x8 vv[4];
#pragma unroll
    for (int u = 0; u < 4; ++u) vv[u] = *(const f16x8*)&vr[u * 8];
    const int c = lane >> 3, e7 = lane & 7;
#pragma unroll
    for (int u = 0; u < 4; ++u)
#pragma unroll
      for (int e = 0; e < 8; ++e) {
        int d = h * 32 + u * 8 + e;
        Vt[d * 64 + ((c ^ e) << 3) + e7] = vv[u][e];  // d&7 == e
      }
  }

  // ---- Q, K fragments direct from global ----
  f16x8 qf[4], kf[4];
#pragma unroll
  for (int it = 0; it < 4; ++it)
    qf[it] = *(const f16x8*)&base[(size_t)(it * 16 + l15) * 576 + h * 32 + g * 8];
#pragma unroll
  for (int jt = 0; jt < 4; ++jt)
    kf[jt] = *(const f16x8*)&base[(size_t)(jt * 16 + l15) * 576 + 192 + h * 32 + g * 8];

  // ---- S = Q K^T ----
  f32x4 S[4][4];
#pragma unroll
  for (int it = 0; it < 4; ++it)
#pragma unroll
    for (int jt = 0; jt < 4; ++jt) S[it][jt] = (f32x4){0.f, 0.f, 0.f, 0.f};
#pragma unroll
  for (int it = 0; it < 4; ++it)
#pragma unroll
    for (int jt = 0; jt < 4; ++jt)
      S[it][jt] = __builtin_amdgcn_mfma_f32_16x16x32_f16(qf[it], kf[jt], S[it][jt], 0, 0, 0);

  // ---- scale + rel-bias + shift mask ----
  const int wi = (w0 + wl) & 255;
  const int wh = wi >> 4, wwc = wi & 15;
  int regj[4];
#pragma unroll
  for (int jt = 0; jt < 4; ++jt) {
    int col = jt * 16 + l15;
    int rj = wh * 8 + (col >> 3), cj = wwc * 8 + (col & 7);
    regj[jt] = (rj < 120 ? 0 : rj < 124 ? 1 : 2) * 3 + (cj < 120 ? 0 : cj < 124 ? 1 : 2);
  }
#pragma unroll
  for (int it = 0; it < 4; ++it) {
    int regi[4];
#pragma unroll
    for (int r = 0; r < 4; ++r) {
      int row = it * 16 + g * 4 + r;
      int ri = wh * 8 + (row >> 3), ci = wwc * 8 + (row & 7);
      regi[r] = (ri < 120 ? 0 : ri < 124 ? 1 : 2) * 3 + (ci < 120 ? 0 : ci < 124 ? 1 : 2);
    }
#pragma unroll
    for (int jt = 0; jt < 4; ++jt) {
      f32x4 bb = *(const f32x4*)&biasF2[(((h * 4 + it) * 4 + jt) * 64 + lane) * 4];
#pragma unroll
      for (int r = 0; r < 4; ++r) {
        float v = S[it][jt][r] * QSCALE + bb[r];
        if (regi[r] != regj[jt]) v -= 100.f;
        S[it][jt][r] = v;
      }
    }
  }

  // ---- softmax: row max (in-reg over jt, then 16-lane butterfly), exp ----
#pragma unroll
  for (int it = 0; it < 4; ++it) {
#pragma unroll
    for (int r = 0; r < 4; ++r) {
      float m = fmaxf(fmaxf(S[it][0][r], S[it][1][r]), fmaxf(S[it][2][r], S[it][3][r]));
#pragma unroll
      for (int off = 1; off < 16; off <<= 1) m = fmaxf(m, __shfl_xor(m, off));
#pragma unroll
      for (int jt = 0; jt < 4; ++jt) S[it][jt][r] = __expf(S[it][jt][r] - m);
    }
  }

  // ---- write P to swizzled LDS ----
  f16* pb = &Pb[h][0];
#pragma unroll
  for (int it = 0; it < 4; ++it)
#pragma unroll
    for (int jt = 0; jt < 4; ++jt)
#pragma unroll
      for (int r = 0; r < 4; ++r) {
        int row = it * 16 + g * 4 + r;
        int cs = (jt * 2 + (l15 >> 3)) ^ (row & 7);
        pb[row * 64 + cs * 8 + (l15 & 7)] = (f16)S[it][jt][r];
      }

  // ---- O = P V (+ row sums via ones-column mfma) ----
  f32x4 O[4][2], Ssum[4];
#pragma unroll
  for (int it = 0; it < 4; ++it) {
    O[it][0] = (f32x4){0.f, 0.f, 0.f, 0.f};
    O[it][1] = (f32x4){0.f, 0.f, 0.f, 0.f};
    Ssum[it] = (f32x4){0.f, 0.f, 0.f, 0.f};
  }
  f16x8 ones;
#pragma unroll
  for (int e = 0; e < 8; ++e) ones[e] = (f16)1.f;
#pragma unroll
  for (int jh = 0; jh < 2; ++jh) {
    const int csw = ((jh * 4 + g) ^ (l15 & 7)) << 3;
    f16x8 pf[4], vf[2];
#pragma unroll
    for (int it = 0; it < 4; ++it) pf[it] = *(const f16x8*)&pb[(it * 16 + l15) * 64 + csw];
#pragma unroll
    for (int dt = 0; dt < 2; ++dt) vf[dt] = *(const f16x8*)&Vt[(h * 32 + dt * 16 + l15) * 64 + csw];
#pragma unroll
    for (int it = 0; it < 4; ++it) {
      O[it][0] = __builtin_amdgcn_mfma_f32_16x16x32_f16(pf[it], vf[0], O[it][0], 0, 0, 0);
      O[it][1] = __builtin_amdgcn_mfma_f32_16x16x32_f16(pf[it], vf[1], O[it][1], 0, 0, 0);
      Ssum[it] = __builtin_amdgcn_mfma_f32_16x16x32_f16(pf[it], ones, Ssum[it], 0, 0, 0);
    }
  }

  // ---- normalize + store ----
#pragma unroll
  for (int it = 0; it < 4; ++it) {
    f32x4 rin;
#pragma unroll
    for (int r = 0; r < 4; ++r) rin[r] = 1.f / Ssum[it][r];
#pragma unroll
    for (int dt = 0; dt < 2; ++dt)
#pragma unroll
      for (int r = 0; r < 4; ++r) {
        int row = it * 16 + g * 4 + r;
        out[(size_t)(wl * 64 + row) * 192 + h * 32 + dt * 16 + l15] =
            (f16)(O[it][dt][r] * rin[r]);
      }
  }
}

// ---------------- host launch ----------------
extern "C" void kernel_launch(void* const* d_in, const int* in_sizes, int n_in,
                              void* d_out, int out_size, void* d_ws, size_t ws_size,
                              hipStream_t stream) {
  const float* x     = (const float*)d_in[0];
  const float* ln1w  = (const float*)d_in[1];
  const float* ln1b  = (const float*)d_in[2];
  const float* qkvw  = (const float*)d_in[3];
  const float* qkvb  = (const float*)d_in[4];
  const float* rpb   = (const float*)d_in[5];
  const float* projw = (const float*)d_in[6];
  const float* projb = (const float*)d_in[7];
  const float* ln2w  = (const float*)d_in[8];
  const float* ln2b  = (const float*)d_in[9];
  const float* fc1w  = (const float*)d_in[10];
  const float* fc1b  = (const float*)d_in[11];
  const float* fc2w  = (const float*)d_in[12];
  const float* fc2b  = (const float*)d_in[13];
  float* out = (float*)d_out;

  // ws layout (B): biasF2 96K | weights hi/lo fp16 ~1.77M | xh 48M | oh 48M | big
  char* ws = (char*)d_ws;
  float* biasF2 = (float*)ws;
  f16* qkvwH = (f16*)(ws + 98304);    f16* qkvwL = qkvwH + 110592;
  f16* projwH = (f16*)(ws + 540672);  f16* projwL = projwH + 36864;
  f16* fc1wH = (f16*)(ws + 688128);   f16* fc1wL = fc1wH + 147456;
  f16* fc2wH = (f16*)(ws + 1277952);  f16* fc2wL = fc2wH + 147456;
  f16* xh    = (f16*)(ws + 1867776);
  f16* oh    = (f16*)(ws + 1867776 + 50331648);
  char* big  = ws + 1867776 + 2 * 50331648;
  size_t R = ws_size > (size_t)(1867776 + 2 * 50331648)
                 ? ws_size - (1867776 + 2 * 50331648) : 0;

  long long wch = (long long)(R / 98304);
  if (wch > NWINtot) wch = NWINtot;
  wch &= ~1LL;
  if (wch < 2) wch = 2;
  long long rch = (long long)(R / 1536);
  if (rch > Mrows) rch = Mrows;
  rch &= ~127LL;
  if (rch < 128) rch = 128;

  wconv_kernel<<<432, 256, 0, stream>>>(qkvw, qkvwH, qkvwL, 192, 576);
  wconv_kernel<<<144, 256, 0, stream>>>(projw, projwH, projwL, 192, 192);
  wconv_kernel<<<576, 256, 0, stream>>>(fc1w, fc1wH, fc1wL, 192, 768);
  wconv_kernel<<<576, 256, 0, stream>>>(fc2w, fc2wH, fc2wL, 768, 192);
  rpb_expand_kernel<<<96, 256, 0, stream>>>(rpb, biasF2);

  ln_prep_kernel<1><<<Mrows / 16, 256, 0, stream>>>(x, ln1w, ln1b, xh, 0);

  f16* qkvc = (f16*)big;
  f16* aoc  = (f16*)(big + (size_t)wch * 73728);
  for (int w = 0; w < NWINtot; w += (int)wch) {
    int cur = (NWINtot - w < (int)wch) ? (NWINtot - w) : (int)wch;
    int rowsc = cur * 64;
    gemm_mfma16<192, 576, 0><<<dim3(3, rowsc / 128), 512, 0, stream>>>(
        xh, qkvwH, qkvwL, qkvb, nullptr, qkvc, w * 64, 0);
    attn_mfma<<<cur, 384, 0, stream>>>(qkvc, biasF2, aoc, w);
    gemm_mfma16<192, 192, 2><<<dim3(1, rowsc / 128), 512, 0, stream>>>(
        aoc, projwH, projwL, projb, x, out, 0, w * 64);
  }

  ln_prep_kernel<0><<<Mrows / 16, 256, 0, stream>>>(out, ln2w, ln2b, oh, 0);

  f16* h1c = (f16*)big;
  for (int r = 0; r < Mrows; r += (int)rch) {
    int cur = (Mrows - r < (int)rch) ? (Mrows - r) : (int)rch;
    gemm_mfma16<192, 768, 1><<<dim3(4, cur / 128), 512, 0, stream>>>(
        oh, fc1wH, fc1wL, fc1b, nullptr, h1c, r, 0);
    gemm_mfma16<768, 192, 3><<<dim3(1, cur / 128), 512, 0, stream>>>(
        h1c, fc2wH, fc2wL, fc2b, out, out, 0, r);
  }
}

// Round 7
// 529.887 us; speedup vs baseline: 4.1571x; 1.3549x over previous
//
#include <hip/hip_runtime.h>
#include <math.h>

typedef _Float16 f16;
typedef _Float16 f16x8 __attribute__((ext_vector_type(8)));
typedef float f32x4 __attribute__((ext_vector_type(4)));

// ---------------- Swin block constants (match reference) ----------------
namespace {
constexpr int Hh = 128, Ww = 128, Cc = 192;
constexpr int NHh = 6;
constexpr int Nn = 64, HDd = 32;
constexpr int SH = 4;
constexpr int Mrows = 131072;
constexpr int NWINtot = 2048;
constexpr float LNEPS = 1e-5f;
constexpr float QSCALE = 0.17677669529663687f;  // 32^-0.5
}

// windowed row m -> original token index (undo roll -4,-4)
__device__ __forceinline__ int win_row_to_src(int m) {
  int tok = m & 63;
  int wi  = m >> 6;
  int ww = wi & 15, wh = (wi >> 4) & 15, b = wi >> 8;
  int r = (wh << 3) + (tok >> 3);
  int c = (ww << 3) + (tok & 7);
  int ro = (r + SH) & (Hh - 1);
  int co = (c + SH) & (Ww - 1);
  return (b << 14) + (ro << 7) + co;
}

// ---------------- fused LN + fp16 convert (+optional window gather) ----------------
template <int GATHER>
__global__ __launch_bounds__(256) void ln_prep_kernel(
    const float* __restrict__ X, const float* __restrict__ lnw,
    const float* __restrict__ lnb, f16* __restrict__ outh, int m0) {
  __shared__ float xr[16][192];
  __shared__ float smu[16], srs[16];
  __shared__ int src[16];
  const int t = threadIdx.x;
  const int r0 = blockIdx.x * 16;
  if (t < 16) {
    int m = m0 + r0 + t;
    src[t] = GATHER ? win_row_to_src(m) : m;
  }
  __syncthreads();
#pragma unroll
  for (int it = 0; it < 3; ++it) {
    int f = t + it * 256;
    int row = f / 48, c4 = f - row * 48;
    float4 v = *(const float4*)&X[(size_t)src[row] * 192 + c4 * 4];
    *(float4*)&xr[row][c4 * 4] = v;
  }
  __syncthreads();
  {
    const int lane = t & 63, w = t >> 6;
    const int g = lane >> 4, li = lane & 15;
    const int row = w * 4 + g;
    float s = 0.f, s2 = 0.f;
#pragma unroll
    for (int j = 0; j < 12; ++j) {
      float v = xr[row][li + j * 16];
      s += v; s2 += v * v;
    }
#pragma unroll
    for (int off = 1; off < 16; off <<= 1) {
      s += __shfl_xor(s, off);
      s2 += __shfl_xor(s2, off);
    }
    if (li == 0) {
      float m = s * (1.f / 192.f);
      smu[row] = m;
      srs[row] = rsqrtf(s2 * (1.f / 192.f) - m * m + LNEPS);
    }
  }
  __syncthreads();
#pragma unroll
  for (int it = 0; it < 2; ++it) {
    int c = t + it * 256;
    if (c < 384) {
      int e0 = c * 8;
      int row = e0 / 192, col = e0 - row * 192;
      float mu_ = smu[row], rs_ = srs[row];
      f16x8 o;
#pragma unroll
      for (int j = 0; j < 8; ++j) {
        float v = (xr[row][col + j] - mu_) * rs_ * lnw[col + j] + lnb[col + j];
        o[j] = (f16)v;
      }
      *(f16x8*)&outh[(size_t)(m0 + r0) * 192 + e0] = o;
    }
  }
}

// ---------------- rel-pos bias in MFMA fragment layout: [h][it][jt][lane][r] ----------------
__global__ __launch_bounds__(256) void rpb_expand_kernel(
    const float* __restrict__ rpb, float* __restrict__ biasF2) {
  int t = blockIdx.x * 256 + threadIdx.x;
  if (t >= NHh * 4 * 4 * 64 * 4) return;
  int r = t & 3, lane = (t >> 2) & 63, jt = (t >> 8) & 3, it = (t >> 10) & 3, h = t >> 12;
  int row = it * 16 + (lane >> 4) * 4 + r;
  int col = jt * 16 + (lane & 15);
  int dh = (row >> 3) - (col >> 3) + 7;
  int dw = (row & 7) - (col & 7) + 7;
  biasF2[t] = rpb[(dh * 15 + dw) * NHh + h];
}

// ---------------- weight transpose + fp16: W[K][N] -> Wt[N][K] ----------------
__global__ __launch_bounds__(256) void wconv_kernel(
    const float* __restrict__ W, f16* __restrict__ hi, int K, int N) {
  int idx = blockIdx.x * 256 + threadIdx.x;
  if (idx >= K * N) return;
  int n = idx / K, k = idx - n * K;
  hi[idx] = (f16)W[(size_t)k * N + n];
}

// ---------------- MFMA GEMM: panel-resident A, barrier-free K-chunk loop ----------------
// BM=128, BN=192; 512 thr = 8 waves (2M x 4N); per-wave 64x48 out.
// A chunk (128 x 192 f16 = 48KB) staged once -> 6 barrier-free k-slices of
// {3 B-frag global loads + 4 ds_read_b128 + 12 MFMA}. K>192 -> multiple chunks.
// EMODE: 0 = +bias -> f16; 1 = +bias,fast-gelu -> f16;
//        2 = +bias+resid f32 scatter win_row_to_src(m0e+m); 3 = +bias+resid f32 at m0e+m
template <int KDIM, int NDIM, int EMODE>
__global__ __launch_bounds__(512, 4) void gemm_mfma16(
    const f16* __restrict__ Abase, const f16* __restrict__ Bt,
    const float* __restrict__ bias, const float* __restrict__ resid,
    void* __restrict__ outp, int m0a, int m0e) {
  constexpr int KC = 192;
  constexpr int NCH = KDIM / KC;
  __shared__ __align__(16) char lds[48 * 1024];  // [ks 6][g 8] subtiles of 16rows x 32k

  const int tid = threadIdx.x;
  const int bn = blockIdx.x * 192;
  const int bm = blockIdx.y * 128;
  const int lane = tid & 63;
  const int wid = tid >> 6;
  const int wr = wid & 1, wc = wid >> 1;
  const int l15 = lane & 15, g2 = lane >> 4;

  // staging: 4 threads/row, 6 x 16B chunks each
  const int srow = tid >> 2;
  const int kq = tid & 3;
  const int sg = srow >> 4;
  const int slot = srow & 15;
  const f16* arow = Abase + (size_t)(m0a + bm + srow) * KDIM;

  f32x4 acc[4][3];
#pragma unroll
  for (int i = 0; i < 4; ++i)
#pragma unroll
    for (int j = 0; j < 3; ++j) acc[i][j] = (f32x4){0.f, 0.f, 0.f, 0.f};

  for (int c = 0; c < NCH; ++c) {
    if (c) __syncthreads();
    // ---- stage A chunk ----
#pragma unroll
    for (int u = 0; u < 6; ++u) {
      int ch = kq + u * 4;                 // 8-elem k-chunk index 0..23
      f16x8 v = *(const f16x8*)&arow[c * KC + ch * 8];
      int ks = ch >> 2, h = ch & 3;
      *(f16x8*)(lds + (ks * 8 + sg) * 1024 + (slot + h * 16) * 16) = v;
    }
    __syncthreads();

    // ---- barrier-free compute over 6 k-slices ----
#pragma unroll
    for (int ks = 0; ks < 6; ++ks) {
      const int kk = c * KC + ks * 32 + g2 * 8;
      f16x8 bf[3];
#pragma unroll
      for (int ni = 0; ni < 3; ++ni) {
        int n = bn + wc * 48 + ni * 16 + l15;
        bf[ni] = *(const f16x8*)&Bt[(size_t)n * KDIM + kk];
      }
#pragma unroll
      for (int mi = 0; mi < 4; ++mi) {
        f16x8 ah = *(const f16x8*)(lds + (ks * 8 + wr * 4 + mi) * 1024 + lane * 16);
#pragma unroll
        for (int ni = 0; ni < 3; ++ni)
          acc[mi][ni] = __builtin_amdgcn_mfma_f32_16x16x32_f16(ah, bf[ni], acc[mi][ni], 0, 0, 0);
      }
    }
  }

  // ---- epilogue: C/D layout col=lane&15, row=(lane>>4)*4+r ----
#pragma unroll
  for (int mi = 0; mi < 4; ++mi) {
#pragma unroll
    for (int ni = 0; ni < 3; ++ni) {
      int col = bn + wc * 48 + ni * 16 + l15;
      float bcol = bias[col];
#pragma unroll
      for (int r = 0; r < 4; ++r) {
        int ml = bm + wr * 64 + mi * 16 + g2 * 4 + r;
        float v = acc[mi][ni][r] + bcol;
        if (EMODE == 0) {
          ((f16*)outp)[(size_t)ml * NDIM + col] = (f16)v;
        } else if (EMODE == 1) {
          // fast gelu: x * sigmoid(1.5957691x(1+0.044715x^2)); max err ~3e-4
          float e = __expf(-1.5957691216f * v * (1.f + 0.044715f * v * v));
          v = v / (1.f + e);
          ((f16*)outp)[(size_t)ml * NDIM + col] = (f16)v;
        } else if (EMODE == 2) {
          int dst = win_row_to_src(m0e + ml);
          ((float*)outp)[(size_t)dst * NDIM + col] = v + resid[(size_t)dst * NDIM + col];
        } else {
          int dst = m0e + ml;
          ((float*)outp)[(size_t)dst * NDIM + col] = v + resid[(size_t)dst * NDIM + col];
        }
      }
    }
  }
}

// ---------------- MFMA windowed attention: block = 1 window x 6 heads (384 thr) ----------------
__global__ __launch_bounds__(384) void attn_mfma(
    const f16* __restrict__ qkv, const float* __restrict__ biasF2,
    f16* __restrict__ out, int w0) {
  __shared__ f16 Vt[192 * 64];       // [d][tok], 16B-chunk XOR swizzle
  __shared__ f16 Pb[NHh][64 * 64];   // per-wave P, same swizzle
  const int t = threadIdx.x;
  const int h = t >> 6;
  const int lane = t & 63;
  const int g = lane >> 4, l15 = lane & 15;
  const int wl = blockIdx.x;
  const f16* base = qkv + (size_t)wl * 64 * 576;

  {
    const f16* vr = base + (size_t)lane * 576 + 384 + h * 32;
    f16x8 vv[4];
#pragma unroll
    for (int u = 0; u < 4; ++u) vv[u] = *(const f16x8*)&vr[u * 8];
    const int c = lane >> 3, e7 = lane & 7;
#pragma unroll
    for (int u = 0; u < 4; ++u)
#pragma unroll
      for (int e = 0; e < 8; ++e) {
        int d = h * 32 + u * 8 + e;
        Vt[d * 64 + ((c ^ e) << 3) + e7] = vv[u][e];  // d&7 == e
      }
  }

  f16x8 qf[4], kf[4];
#pragma unroll
  for (int it = 0; it < 4; ++it)
    qf[it] = *(const f16x8*)&base[(size_t)(it * 16 + l15) * 576 + h * 32 + g * 8];
#pragma unroll
  for (int jt = 0; jt < 4; ++jt)
    kf[jt] = *(const f16x8*)&base[(size_t)(jt * 16 + l15) * 576 + 192 + h * 32 + g * 8];

  f32x4 S[4][4];
#pragma unroll
  for (int it = 0; it < 4; ++it)
#pragma unroll
    for (int jt = 0; jt < 4; ++jt) S[it][jt] = (f32x4){0.f, 0.f, 0.f, 0.f};
#pragma unroll
  for (int it = 0; it < 4; ++it)
#pragma unroll
    for (int jt = 0; jt < 4; ++jt)
      S[it][jt] = __builtin_amdgcn_mfma_f32_16x16x32_f16(qf[it], kf[jt], S[it][jt], 0, 0, 0);

  const int wi = (w0 + wl) & 255;
  const int wh = wi >> 4, wwc = wi & 15;
  int regj[4];
#pragma unroll
  for (int jt = 0; jt < 4; ++jt) {
    int col = jt * 16 + l15;
    int rj = wh * 8 + (col >> 3), cj = wwc * 8 + (col & 7);
    regj[jt] = (rj < 120 ? 0 : rj < 124 ? 1 : 2) * 3 + (cj < 120 ? 0 : cj < 124 ? 1 : 2);
  }
#pragma unroll
  for (int it = 0; it < 4; ++it) {
    int regi[4];
#pragma unroll
    for (int r = 0; r < 4; ++r) {
      int row = it * 16 + g * 4 + r;
      int ri = wh * 8 + (row >> 3), ci = wwc * 8 + (row & 7);
      regi[r] = (ri < 120 ? 0 : ri < 124 ? 1 : 2) * 3 + (ci < 120 ? 0 : ci < 124 ? 1 : 2);
    }
#pragma unroll
    for (int jt = 0; jt < 4; ++jt) {
      f32x4 bb = *(const f32x4*)&biasF2[(((h * 4 + it) * 4 + jt) * 64 + lane) * 4];
#pragma unroll
      for (int r = 0; r < 4; ++r) {
        float v = S[it][jt][r] * QSCALE + bb[r];
        if (regi[r] != regj[jt]) v -= 100.f;
        S[it][jt][r] = v;
      }
    }
  }

#pragma unroll
  for (int it = 0; it < 4; ++it) {
#pragma unroll
    for (int r = 0; r < 4; ++r) {
      float m = fmaxf(fmaxf(S[it][0][r], S[it][1][r]), fmaxf(S[it][2][r], S[it][3][r]));
#pragma unroll
      for (int off = 1; off < 16; off <<= 1) m = fmaxf(m, __shfl_xor(m, off));
#pragma unroll
      for (int jt = 0; jt < 4; ++jt) S[it][jt][r] = __expf(S[it][jt][r] - m);
    }
  }

  f16* pb = &Pb[h][0];
#pragma unroll
  for (int it = 0; it < 4; ++it)
#pragma unroll
    for (int jt = 0; jt < 4; ++jt)
#pragma unroll
      for (int r = 0; r < 4; ++r) {
        int row = it * 16 + g * 4 + r;
        int cs = (jt * 2 + (l15 >> 3)) ^ (row & 7);
        pb[row * 64 + cs * 8 + (l15 & 7)] = (f16)S[it][jt][r];
      }

  f32x4 O[4][2], Ssum[4];
#pragma unroll
  for (int it = 0; it < 4; ++it) {
    O[it][0] = (f32x4){0.f, 0.f, 0.f, 0.f};
    O[it][1] = (f32x4){0.f, 0.f, 0.f, 0.f};
    Ssum[it] = (f32x4){0.f, 0.f, 0.f, 0.f};
  }
  f16x8 ones;
#pragma unroll
  for (int e = 0; e < 8; ++e) ones[e] = (f16)1.f;
#pragma unroll
  for (int jh = 0; jh < 2; ++jh) {
    const int csw = ((jh * 4 + g) ^ (l15 & 7)) << 3;
    f16x8 pf[4], vf[2];
#pragma unroll
    for (int it = 0; it < 4; ++it) pf[it] = *(const f16x8*)&pb[(it * 16 + l15) * 64 + csw];
#pragma unroll
    for (int dt = 0; dt < 2; ++dt) vf[dt] = *(const f16x8*)&Vt[(h * 32 + dt * 16 + l15) * 64 + csw];
#pragma unroll
    for (int it = 0; it < 4; ++it) {
      O[it][0] = __builtin_amdgcn_mfma_f32_16x16x32_f16(pf[it], vf[0], O[it][0], 0, 0, 0);
      O[it][1] = __builtin_amdgcn_mfma_f32_16x16x32_f16(pf[it], vf[1], O[it][1], 0, 0, 0);
      Ssum[it] = __builtin_amdgcn_mfma_f32_16x16x32_f16(pf[it], ones, Ssum[it], 0, 0, 0);
    }
  }

#pragma unroll
  for (int it = 0; it < 4; ++it) {
    f32x4 rin;
#pragma unroll
    for (int r = 0; r < 4; ++r) rin[r] = 1.f / Ssum[it][r];
#pragma unroll
    for (int dt = 0; dt < 2; ++dt)
#pragma unroll
      for (int r = 0; r < 4; ++r) {
        int row = it * 16 + g * 4 + r;
        out[(size_t)(wl * 64 + row) * 192 + h * 32 + dt * 16 + l15] =
            (f16)(O[it][dt][r] * rin[r]);
      }
  }
}

// ---------------- host launch ----------------
extern "C" void kernel_launch(void* const* d_in, const int* in_sizes, int n_in,
                              void* d_out, int out_size, void* d_ws, size_t ws_size,
                              hipStream_t stream) {
  const float* x     = (const float*)d_in[0];
  const float* ln1w  = (const float*)d_in[1];
  const float* ln1b  = (const float*)d_in[2];
  const float* qkvw  = (const float*)d_in[3];
  const float* qkvb  = (const float*)d_in[4];
  const float* rpb   = (const float*)d_in[5];
  const float* projw = (const float*)d_in[6];
  const float* projb = (const float*)d_in[7];
  const float* ln2w  = (const float*)d_in[8];
  const float* ln2b  = (const float*)d_in[9];
  const float* fc1w  = (const float*)d_in[10];
  const float* fc1b  = (const float*)d_in[11];
  const float* fc2w  = (const float*)d_in[12];
  const float* fc2b  = (const float*)d_in[13];
  float* out = (float*)d_out;

  // ws layout (B): biasF2 96K | Wt f16: qkv 221184, proj 73728, fc1 294912, fc2 294912 | xh | oh | big
  char* ws = (char*)d_ws;
  float* biasF2 = (float*)ws;
  f16* qkvwT = (f16*)(ws + 98304);
  f16* projwT = (f16*)(ws + 319488);
  f16* fc1wT = (f16*)(ws + 393216);
  f16* fc2wT = (f16*)(ws + 688128);
  f16* xh    = (f16*)(ws + 983040);
  f16* oh    = (f16*)(ws + 983040 + 50331648);
  char* big  = ws + 983040 + 2 * 50331648;
  size_t R = ws_size > (size_t)(983040 + 2 * 50331648)
                 ? ws_size - (983040 + 2 * 50331648) : 0;

  long long wch = (long long)(R / 98304);
  if (wch > NWINtot) wch = NWINtot;
  wch &= ~1LL;
  if (wch < 2) wch = 2;
  long long rch = (long long)(R / 1536);
  if (rch > Mrows) rch = Mrows;
  rch &= ~127LL;
  if (rch < 128) rch = 128;

  wconv_kernel<<<432, 256, 0, stream>>>(qkvw, qkvwT, 192, 576);
  wconv_kernel<<<144, 256, 0, stream>>>(projw, projwT, 192, 192);
  wconv_kernel<<<576, 256, 0, stream>>>(fc1w, fc1wT, 192, 768);
  wconv_kernel<<<576, 256, 0, stream>>>(fc2w, fc2wT, 768, 192);
  rpb_expand_kernel<<<96, 256, 0, stream>>>(rpb, biasF2);

  ln_prep_kernel<1><<<Mrows / 16, 256, 0, stream>>>(x, ln1w, ln1b, xh, 0);

  f16* qkvc = (f16*)big;
  f16* aoc  = (f16*)(big + (size_t)wch * 73728);
  for (int w = 0; w < NWINtot; w += (int)wch) {
    int cur = (NWINtot - w < (int)wch) ? (NWINtot - w) : (int)wch;
    int rowsc = cur * 64;
    gemm_mfma16<192, 576, 0><<<dim3(3, rowsc / 128), 512, 0, stream>>>(
        xh, qkvwT, qkvb, nullptr, qkvc, w * 64, 0);
    attn_mfma<<<cur, 384, 0, stream>>>(qkvc, biasF2, aoc, w);
    gemm_mfma16<192, 192, 2><<<dim3(1, rowsc / 128), 512, 0, stream>>>(
        aoc, projwT, projb, x, out, 0, w * 64);
  }

  ln_prep_kernel<0><<<Mrows / 16, 256, 0, stream>>>(out, ln2w, ln2b, oh, 0);

  f16* h1c = (f16*)big;
  for (int r = 0; r < Mrows; r += (int)rch) {
    int cur = (Mrows - r < (int)rch) ? (Mrows - r) : (int)rch;
    gemm_mfma16<192, 768, 1><<<dim3(4, cur / 128), 512, 0, stream>>>(
        oh, fc1wT, fc1b, nullptr, h1c, r, 0);
    gemm_mfma16<768, 192, 3><<<dim3(1, cur / 128), 512, 0, stream>>>(
        h1c, fc2wT, fc2b, out, out, 0, r);
  }
}